// Round 8
// baseline (658.816 us; speedup 1.0000x reference)
//
#include <hip/hip_runtime.h>
#include <cstdint>

typedef __attribute__((ext_vector_type(8))) short short8;
typedef __attribute__((ext_vector_type(4))) short short4v;
typedef __attribute__((ext_vector_type(4))) float f32x4;

// ---------------------------------------------------------------------------
// threefry (partitionable scheme) -- verified bit-exact (absmax 0.0, r2-r4)
// ---------------------------------------------------------------------------
__host__ __device__ __forceinline__ void tf2x32(uint32_t k0, uint32_t k1,
                                                uint32_t x0, uint32_t x1,
                                                uint32_t& o0, uint32_t& o1) {
  const uint32_t ks2 = k0 ^ k1 ^ 0x1BD11BDAu;
#define TF_R(r) { x0 += x1; x1 = (x1 << (r)) | (x1 >> (32 - (r))); x1 ^= x0; }
  x0 += k0; x1 += k1;
  TF_R(13) TF_R(15) TF_R(26) TF_R(6)
  x0 += k1;  x1 += ks2 + 1u;
  TF_R(17) TF_R(29) TF_R(16) TF_R(24)
  x0 += ks2; x1 += k0 + 2u;
  TF_R(13) TF_R(15) TF_R(26) TF_R(6)
  x0 += k0;  x1 += k1 + 3u;
  TF_R(17) TF_R(29) TF_R(16) TF_R(24)
  x0 += k1;  x1 += ks2 + 4u;
  TF_R(13) TF_R(15) TF_R(26) TF_R(6)
  x0 += ks2; x1 += k0 + 5u;
#undef TF_R
  o0 = x0; o1 = x1;
}

__device__ __forceinline__ uint32_t rb32(uint32_t k0, uint32_t k1, uint32_t idx) {
  uint32_t a, b;
  tf2x32(k0, k1, 0u, idx, a, b);
  return a ^ b;
}

__device__ __forceinline__ float neg_log_unif(uint32_t bits) {
  float u = __uint_as_float((bits >> 9) | 0x3f800000u) - 1.0f;
  u = fmaxf(u, 1.17549435e-38f);
  return -__logf(u);
}

// bf16 split helpers (RNE)
__device__ __host__ __forceinline__ ushort f2bf(float f) {
  uint32_t x;
  __builtin_memcpy(&x, &f, 4);
  return (ushort)((x + 0x7fffu + ((x >> 16) & 1u)) >> 16);
}
__device__ __forceinline__ float bf2f(ushort h) {
  return __uint_as_float(((uint32_t)h) << 16);
}

// ---------------------------------------------------------------------------
// Convert conv2 weights -> tap-major split bf16: w2T[tap][oc][ic] hi/lo.
// ---------------------------------------------------------------------------
__global__ __launch_bounds__(256) void convert_w2(const float* __restrict__ w,
                                                  ushort* __restrict__ wh,
                                                  ushort* __restrict__ wl) {
  const int i = blockIdx.x * 256 + threadIdx.x;   // (tap*64 + oc)*32 + ic
  if (i < 51200) {
    const int ic = i & 31, oc = (i >> 5) & 63, tap = i >> 11;
    const float f = w[oc * 800 + ic * 25 + tap];
    const ushort h = f2bf(f);
    wh[i] = h;
    wl[i] = f2bf(f - bf2f(h));
  }
}

// ---------------------------------------------------------------------------
// Convert fc1 weights: [k][n] f32 -> transposed split bf16 [n][k] hi/lo.
// ---------------------------------------------------------------------------
__global__ __launch_bounds__(256) void convert_w1T(const float* __restrict__ w,
                                                   ushort* __restrict__ th,
                                                   ushort* __restrict__ tl) {
  __shared__ float tile[32][33];
  const int t = threadIdx.x;
  const int bi = blockIdx.x >> 5, bj = blockIdx.x & 31;   // k-tile, n-tile
  const int r = t >> 3, c = (t & 7) * 4;
  const float4 v = *(const float4*)&w[(size_t)(bi * 32 + r) * 1024 + bj * 32 + c];
  tile[r][c + 0] = v.x; tile[r][c + 1] = v.y;
  tile[r][c + 2] = v.z; tile[r][c + 3] = v.w;
  __syncthreads();
  const int n = bj * 32 + r;
  float u[4];
#pragma unroll
  for (int q = 0; q < 4; ++q) u[q] = tile[c + q][r];
  short4v hv, lv;
#pragma unroll
  for (int q = 0; q < 4; ++q) {
    const ushort h = f2bf(u[q]);
    hv[q] = (short)h;
    lv[q] = (short)f2bf(u[q] - bf2f(h));
  }
  *(short4v*)&th[(size_t)n * 1024 + bi * 32 + c] = hv;
  *(short4v*)&tl[(size_t)n * 1024 + bi * 32 + c] = lv;
}

// ---------------------------------------------------------------------------
// Kernel A: conv1(5x5)+pool on VALU (split-written), conv2 as tap-major
// split-bf16 MFMA with weights DIRECT FROM L2 (no LDS staging, no barriers
// in the tap loop; B-frags register-double-buffered across tap pairs).
// One image per block, 256 threads. LDS ~29.8KB.
// ---------------------------------------------------------------------------
__global__ __launch_bounds__(256, 4) void conv_fused(
    const float* __restrict__ aimg, const float* __restrict__ bimg,
    const float* __restrict__ w1, const float* __restrict__ b1,
    const ushort* __restrict__ w2h, const ushort* __restrict__ w2l,
    const float* __restrict__ b2,
    ushort* __restrict__ p2h, ushort* __restrict__ p2l, int B) {
  __shared__ __align__(16) char smem[6336];  // {img 784f + w1s 800f} | {ob 1024f}
  __shared__ ushort buf1h[144 * 40];   // conv1 out split hi: [pix][ic] pad40
  __shared__ ushort buf1l[144 * 40];
  __shared__ float b1s[32];
  __shared__ float b2s[64];

  float* img = (float*)smem;            // [784]
  float* w1s = img + 784;               // [800]
  float* ob = (float*)smem;             // [1024] epilogue staging

  const int t = threadIdx.x;
  const int im = blockIdx.x;
  const float* src = (im < B) ? (aimg + (size_t)im * 784)
                              : (bimg + (size_t)(im - B) * 784);
  for (int i = t; i < 784; i += 256) img[i] = src[i];
  for (int i = t; i < 800; i += 256) w1s[i] = w1[i];
  if (t < 32) b1s[t] = b1[t];
  if (t >= 64 && t < 128) b2s[t - 64] = b2[t - 64];
  __syncthreads();

  // ---- conv1 + pool: thread t -> ic=t>>3 (32), sub=t&7; 18 pooled px each.
  {
    const int ic = t >> 3, sub = t & 7;
    float w[25];
#pragma unroll
    for (int k = 0; k < 25; ++k) w[k] = w1s[ic * 25 + k];
    const float bias = b1s[ic];
#pragma unroll 1
    for (int j = 0; j < 18; ++j) {
      const int p = sub + (j << 3);          // 0..143
      const int ph = p / 12, pw = p - ph * 12;
      const int y0 = ph << 1, x0 = pw << 1;
      float patch[36];
#pragma unroll
      for (int r = 0; r < 6; ++r)
#pragma unroll
        for (int c = 0; c < 6; ++c)
          patch[r * 6 + c] = img[(y0 + r) * 28 + x0 + c];
      float m = -3.0e38f;
#pragma unroll
      for (int dy = 0; dy < 2; ++dy)
#pragma unroll
        for (int dx = 0; dx < 2; ++dx) {
          float acc = 0.f;
#pragma unroll
          for (int kh = 0; kh < 5; ++kh)
#pragma unroll
            for (int kw = 0; kw < 5; ++kw)
              acc += w[kh * 5 + kw] * patch[(dy + kh) * 6 + (dx + kw)];
          m = fmaxf(m, acc);
        }
      const float fv = m + bias;
      const ushort h = f2bf(fv);
      buf1h[p * 40 + ic] = h;
      buf1l[p * 40 + ic] = f2bf(fv - bf2f(h));
    }
  }
  __syncthreads();   // buf1 complete; img/w1s dead from here on

  // ---- conv2: tap-major MFMA, barrier-free. Wave grid 2x2 (wm px, wn oc).
  const int l = t & 63, wv = t >> 6;
  const int wm = wv >> 1, wn = wv & 1;
  const int ii = l & 15, gi = l >> 4;
  const int px0 = 32 * wm + ii, px1 = px0 + 16;
  const int ra0 = (px0 >> 3) * 12 + (px0 & 7);   // pix at tap(0,0)
  const int ra1 = (px1 >> 3) * 12 + (px1 & 7);
  // per-lane global weight base: row oc = 32*wn + ii (+16 per nt), k = 8*gi
  const ushort* wbh = w2h + (size_t)(32 * wn + ii) * 32 + 8 * gi;
  const ushort* wbl = w2l + (size_t)(32 * wn + ii) * 32 + 8 * gi;

  f32x4 acc[2][2];
#pragma unroll
  for (int a = 0; a < 2; ++a)
#pragma unroll
    for (int b = 0; b < 2; ++b) acc[a][b] = (f32x4){0.f, 0.f, 0.f, 0.f};

#define LOADB(dst, tap_) {                                                   \
    dst[0] = *(const short8*)(wbh + (tap_) * 2048);                          \
    dst[1] = *(const short8*)(wbh + (tap_) * 2048 + 512);                    \
    dst[2] = *(const short8*)(wbl + (tap_) * 2048);                          \
    dst[3] = *(const short8*)(wbl + (tap_) * 2048 + 512);                    }

#define BODY(tap_, bf) {                                                     \
    const int kh_ = ((tap_) * 205) >> 10;                                    \
    const int pb_ = kh_ * 12 + ((tap_) - kh_ * 5);                           \
    const short8 ah0 = *(const short8*)&buf1h[(ra0 + pb_) * 40 + 8 * gi];    \
    const short8 al0 = *(const short8*)&buf1l[(ra0 + pb_) * 40 + 8 * gi];    \
    const short8 ah1 = *(const short8*)&buf1h[(ra1 + pb_) * 40 + 8 * gi];    \
    const short8 al1 = *(const short8*)&buf1l[(ra1 + pb_) * 40 + 8 * gi];    \
    acc[0][0] = __builtin_amdgcn_mfma_f32_16x16x32_bf16(ah0, bf[0], acc[0][0], 0, 0, 0); \
    acc[0][0] = __builtin_amdgcn_mfma_f32_16x16x32_bf16(al0, bf[0], acc[0][0], 0, 0, 0); \
    acc[0][0] = __builtin_amdgcn_mfma_f32_16x16x32_bf16(ah0, bf[2], acc[0][0], 0, 0, 0); \
    acc[0][1] = __builtin_amdgcn_mfma_f32_16x16x32_bf16(ah0, bf[1], acc[0][1], 0, 0, 0); \
    acc[0][1] = __builtin_amdgcn_mfma_f32_16x16x32_bf16(al0, bf[1], acc[0][1], 0, 0, 0); \
    acc[0][1] = __builtin_amdgcn_mfma_f32_16x16x32_bf16(ah0, bf[3], acc[0][1], 0, 0, 0); \
    acc[1][0] = __builtin_amdgcn_mfma_f32_16x16x32_bf16(ah1, bf[0], acc[1][0], 0, 0, 0); \
    acc[1][0] = __builtin_amdgcn_mfma_f32_16x16x32_bf16(al1, bf[0], acc[1][0], 0, 0, 0); \
    acc[1][0] = __builtin_amdgcn_mfma_f32_16x16x32_bf16(ah1, bf[2], acc[1][0], 0, 0, 0); \
    acc[1][1] = __builtin_amdgcn_mfma_f32_16x16x32_bf16(ah1, bf[1], acc[1][1], 0, 0, 0); \
    acc[1][1] = __builtin_amdgcn_mfma_f32_16x16x32_bf16(al1, bf[1], acc[1][1], 0, 0, 0); \
    acc[1][1] = __builtin_amdgcn_mfma_f32_16x16x32_bf16(ah1, bf[3], acc[1][1], 0, 0, 0); }

  {
    short8 fb0[4], fb1[4];
    LOADB(fb0, 0);
#pragma unroll 1
    for (int tp = 0; tp < 12; ++tp) {
      const int tap = 2 * tp;
      LOADB(fb1, tap + 1);
      BODY(tap, fb0);
      LOADB(fb0, tap + 2);      // tp=11 loads tap 24
      BODY(tap + 1, fb1);
    }
    BODY(24, fb0);
  }
#undef LOADB
#undef BODY

  // pool 2x2 + bias -> ob[oc*16 + ph*4 + pw]  (no barrier needed before
  // writes: ob aliases img/w1s which are dead; buf1 is untouched)
#pragma unroll
  for (int mt = 0; mt < 2; ++mt)
#pragma unroll
    for (int nt = 0; nt < 2; ++nt)
#pragma unroll
      for (int j = 0; j < 2; ++j) {
        const float hm = fmaxf(acc[mt][nt][2 * j], acc[mt][nt][2 * j + 1]);
        const float vm = fmaxf(hm, __shfl_xor(hm, 32));
        if (gi < 2) {
          const int oc = 32 * wn + 16 * nt + ii;
          ob[oc * 16 + (2 * wm + mt) * 4 + 2 * gi + j] = vm + b2s[oc];
        }
      }
  __syncthreads();

  // split bf16 output (feeds fc1 MFMA directly)
  const float4 v = *(const float4*)&ob[4 * t];
  short4v hv, lv;
  const float* vp = (const float*)&v;
#pragma unroll
  for (int q = 0; q < 4; ++q) {
    const ushort h = f2bf(vp[q]);
    hv[q] = (short)h;
    lv[q] = (short)f2bf(vp[q] - bf2f(h));
  }
  *(short4v*)&p2h[(size_t)im * 1024 + 4 * t] = hv;
  *(short4v*)&p2l[(size_t)im * 1024 + 4 * t] = lv;
}

// ---------------------------------------------------------------------------
// Kernel C: fc1 split-bf16 MFMA: out = relu(A[8192,1024] @ W[1024,1024] + b)
// 128x128 tile, BK=32. A double-buffered in LDS (1 barrier/kstep);
// B-frags direct from L2.
// ---------------------------------------------------------------------------
__global__ __launch_bounds__(256, 3) void fc1_mfma(
    const ushort* __restrict__ ah_g, const ushort* __restrict__ al_g,
    const ushort* __restrict__ wh_g, const ushort* __restrict__ wl_g,
    const float* __restrict__ bias, float* __restrict__ out) {
  __shared__ ushort Ah[2][128 * 40], Al[2][128 * 40];   // 40960B
  const int t = threadIdx.x;
  const int bx = blockIdx.x & 7, by = blockIdx.x >> 3;
  const int m0 = by * 128, n0 = bx * 128;
  const int l = t & 63, wv = t >> 6;
  const int wm = wv >> 1, wn = wv & 1;
  const int ii = l & 15, gi = l >> 4;
  const int sr = t >> 1, sk = (t & 1) * 16;    // stage: row, k-offset

  const ushort* pwh = wh_g + (size_t)(n0 + 64 * wn + ii) * 1024 + 8 * gi;
  const ushort* pwl = wl_g + (size_t)(n0 + 64 * wn + ii) * 1024 + 8 * gi;

  f32x4 acc[4][4];
#pragma unroll
  for (int a = 0; a < 4; ++a)
#pragma unroll
    for (int b = 0; b < 4; ++b) acc[a][b] = (f32x4){0.f, 0.f, 0.f, 0.f};

  float bias_r[4];
#pragma unroll
  for (int nt = 0; nt < 4; ++nt)
    bias_r[nt] = bias[n0 + 64 * wn + 16 * nt + ii];

  // prologue: load k0=0 A-tiles to regs
  short8 ga0 = *(const short8*)&ah_g[(size_t)(m0 + sr) * 1024 + sk];
  short8 ga1 = *(const short8*)&ah_g[(size_t)(m0 + sr) * 1024 + sk + 8];
  short8 ga2 = *(const short8*)&al_g[(size_t)(m0 + sr) * 1024 + sk];
  short8 ga3 = *(const short8*)&al_g[(size_t)(m0 + sr) * 1024 + sk + 8];

#pragma unroll 1
  for (int k0 = 0; k0 < 1024; k0 += 32) {
    const int sl = (k0 >> 5) & 1;
    *(short8*)&Ah[sl][sr * 40 + sk] = ga0;
    *(short8*)&Ah[sl][sr * 40 + sk + 8] = ga1;
    *(short8*)&Al[sl][sr * 40 + sk] = ga2;
    *(short8*)&Al[sl][sr * 40 + sk + 8] = ga3;
    const int kn = (k0 + 32 < 1024) ? k0 + 32 : 0;   // prefetch next (wraps)
    ga0 = *(const short8*)&ah_g[(size_t)(m0 + sr) * 1024 + kn + sk];
    ga1 = *(const short8*)&ah_g[(size_t)(m0 + sr) * 1024 + kn + sk + 8];
    ga2 = *(const short8*)&al_g[(size_t)(m0 + sr) * 1024 + kn + sk];
    ga3 = *(const short8*)&al_g[(size_t)(m0 + sr) * 1024 + kn + sk + 8];
    __syncthreads();   // slot sl staged

    short8 bh[4], bl[4];
#pragma unroll
    for (int nt = 0; nt < 4; ++nt) {
      bh[nt] = *(const short8*)(pwh + nt * 16384 + k0);
      bl[nt] = *(const short8*)(pwl + nt * 16384 + k0);
    }
#pragma unroll
    for (int mt = 0; mt < 4; ++mt) {
      const short8 ah = *(const short8*)&Ah[sl][(64 * wm + 16 * mt + ii) * 40 + 8 * gi];
      const short8 al = *(const short8*)&Al[sl][(64 * wm + 16 * mt + ii) * 40 + 8 * gi];
#pragma unroll
      for (int nt = 0; nt < 4; ++nt) {
        acc[mt][nt] = __builtin_amdgcn_mfma_f32_16x16x32_bf16(ah, bh[nt], acc[mt][nt], 0, 0, 0);
        acc[mt][nt] = __builtin_amdgcn_mfma_f32_16x16x32_bf16(al, bh[nt], acc[mt][nt], 0, 0, 0);
        acc[mt][nt] = __builtin_amdgcn_mfma_f32_16x16x32_bf16(ah, bl[nt], acc[mt][nt], 0, 0, 0);
      }
    }
  }

  // epilogue: bias + relu
#pragma unroll
  for (int mt = 0; mt < 4; ++mt) {
    const int rbase = m0 + 64 * wm + 16 * mt + 4 * gi;
#pragma unroll
    for (int nt = 0; nt < 4; ++nt) {
      const int c = n0 + 64 * wn + 16 * nt + ii;
#pragma unroll
      for (int reg = 0; reg < 4; ++reg)
        out[(size_t)(rbase + reg) * 1024 + c] =
            fmaxf(acc[mt][nt][reg] + bias_r[nt], 0.f);
    }
  }
}

// ---------------------------------------------------------------------------
// Kernel D: fc2 (1024->10) + softmax. One wave per row.
// ---------------------------------------------------------------------------
__global__ __launch_bounds__(64) void fc2_softmax(const float* __restrict__ X,
                                                  const float* __restrict__ W,
                                                  const float* __restrict__ bias,
                                                  float* __restrict__ distrs,
                                                  float* __restrict__ invp) {
  const int row = blockIdx.x, l = threadIdx.x;
  const float* x = X + (size_t)row * 1024;
  float acc[10];
#pragma unroll
  for (int c = 0; c < 10; ++c) acc[c] = 0.f;
  for (int k = l; k < 1024; k += 64) {
    const float xv = x[k];
    const float* wr = W + (size_t)k * 10;
#pragma unroll
    for (int c = 0; c < 10; ++c) acc[c] += xv * wr[c];
  }
#pragma unroll
  for (int c = 0; c < 10; ++c) {
    float v = acc[c];
#pragma unroll
    for (int off = 32; off > 0; off >>= 1) v += __shfl_xor(v, off, 64);
    acc[c] = v;
  }
  float z[10], m = -3.0e38f;
#pragma unroll
  for (int c = 0; c < 10; ++c) { z[c] = acc[c] + bias[c]; m = fmaxf(m, z[c]); }
  float s = 0.f, e[10];
#pragma unroll
  for (int c = 0; c < 10; ++c) { e[c] = __expf(z[c] - m); s += e[c]; }
  if (l < 10) {
    distrs[(size_t)row * 10 + l] = e[l] / s;
    invp[(size_t)row * 10 + l] = s / e[l];
  }
}

// ---------------------------------------------------------------------------
// Kernel E: threefry categorical + masked hist + per-row MSE partials.
// ---------------------------------------------------------------------------
__global__ __launch_bounds__(512) void sample_hist_mse(
    const float* __restrict__ distrs, const float* __restrict__ invp,
    const int* __restrict__ y, const int* __restrict__ nsamp,
    float* __restrict__ out, int B,
    uint32_t ka0, uint32_t ka1, uint32_t kb0, uint32_t kb1) {
  const int brow = blockIdx.x, tid = threadIdx.x;
  __shared__ float ipa[10], ipb[10], part[10];
  __shared__ int ha[10], tot;
  if (tid < 10) { ipa[tid] = invp[(size_t)brow * 10 + tid]; ha[tid] = 0; }
  else if (tid < 20) ipb[tid - 10] = invp[(size_t)(B + brow) * 10 + (tid - 10)];
  else if (tid == 20) tot = 0;
  __syncthreads();
  const int yy = y[brow];
  const int S = nsamp[0];
  for (int s0 = 0; s0 < S; s0 += 512) {
    const int s = s0 + tid;
    if (s >= S) break;
    const uint32_t base = ((uint32_t)s * (uint32_t)B + (uint32_t)brow) * 10u;
    float bestA = __builtin_inff(), bestB = __builtin_inff();
    int as = 0, bs = 0;
#pragma unroll
    for (int c = 0; c < 10; ++c) {
      const float va = neg_log_unif(rb32(ka0, ka1, base + (uint32_t)c)) * ipa[c];
      if (va < bestA) { bestA = va; as = c; }
      const float vb = neg_log_unif(rb32(kb0, kb1, base + (uint32_t)c)) * ipb[c];
      if (vb < bestB) { bestB = vb; bs = c; }
    }
    if (bs == yy && as >= bs) { atomicAdd(&ha[as], 1); atomicAdd(&tot, 1); }
  }
  __syncthreads();
  if (tid < 10) {
    const int tc = tot;
    const float denom = fmaxf((float)tc, 1.0f);
    const float ap = (tc > 0) ? (float)ha[tid] / denom : 0.0f;
    const float bp = (tc > 0 && tid == yy) ? ((float)tc / denom) : 0.0f;
    const float da = distrs[(size_t)brow * 10 + tid] - ap;
    const float db = distrs[(size_t)(B + brow) * 10 + tid] - bp;
    part[tid] = da * da + db * db;
  }
  __syncthreads();
  if (tid == 0) {
    float sum = 0.f;
#pragma unroll
    for (int i = 0; i < 10; ++i) sum += part[i];
    atomicAdd(out, sum);
  }
}

__global__ void finalize_mean(float* out, float n) { out[0] = out[0] / n; }

// ---------------------------------------------------------------------------
extern "C" void kernel_launch(void* const* d_in, const int* in_sizes, int n_in,
                              void* d_out, int out_size, void* d_ws, size_t ws_size,
                              hipStream_t stream) {
  (void)n_in; (void)out_size; (void)ws_size;
  const float* a_imgs = (const float*)d_in[0];
  const float* b_imgs = (const float*)d_in[1];
  const float* c1w = (const float*)d_in[2];
  const float* c1b = (const float*)d_in[3];
  const float* c2w = (const float*)d_in[4];
  const float* c2b = (const float*)d_in[5];
  const float* f1w = (const float*)d_in[6];
  const float* f1b = (const float*)d_in[7];
  const float* f2w = (const float*)d_in[8];
  const float* f2b = (const float*)d_in[9];
  const int* y = (const int*)d_in[10];
  const int* nsamp = (const int*)d_in[11];

  const int B = in_sizes[0] / 784;   // 4096
  const int R = 2 * B;               // 8192 images

  char* ws = (char*)d_ws;
  ushort* p2h   = (ushort*)ws;                          // [8192*1024] 16.78MB
  ushort* p2l   = p2h + (size_t)R * 1024;               // 16.78MB
  float* fc1out = (float*)(p2l + (size_t)R * 1024);     // 33.55MB
  ushort* f1wTh = (ushort*)(fc1out + (size_t)R * 1024); // 2.10MB
  ushort* f1wTl = f1wTh + 1024 * 1024;                  // 2.10MB
  ushort* w2hT  = f1wTl + 1024 * 1024;                  // 102KB
  ushort* w2lT  = w2hT + 51200;                         // 102KB
  float* distrs = (float*)(w2lT + 51200);               // 328KB
  float* invp   = distrs + (size_t)R * 10;              // 328KB

  uint32_t ka0, ka1, kb0, kb1;
  tf2x32(0u, 42u, 0u, 0u, ka0, ka1);
  tf2x32(0u, 42u, 0u, 1u, kb0, kb1);

  hipMemsetAsync(d_out, 0, sizeof(float), stream);
  convert_w2<<<200, 256, 0, stream>>>(c2w, w2hT, w2lT);
  convert_w1T<<<1024, 256, 0, stream>>>(f1w, f1wTh, f1wTl);
  conv_fused<<<R, 256, 0, stream>>>(a_imgs, b_imgs, c1w, c1b, w2hT, w2lT, c2b,
                                    p2h, p2l, B);
  fc1_mfma<<<512, 256, 0, stream>>>(p2h, p2l, f1wTh, f1wTl, f1b, fc1out);
  fc2_softmax<<<R, 64, 0, stream>>>(fc1out, f2w, f2b, distrs, invp);
  sample_hist_mse<<<B, 512, 0, stream>>>(distrs, invp, y, nsamp, (float*)d_out, B,
                                         ka0, ka1, kb0, kb1);
  finalize_mean<<<1, 1, 0, stream>>>((float*)d_out, (float)R * 10.0f);
}